// Round 9
// baseline (502.656 us; speedup 1.0000x reference)
//
#include <hip/hip_runtime.h>
#include <hip/hip_bf16.h>
#include <math.h>

typedef __hip_bfloat16 bf16;
typedef unsigned short u16;
typedef unsigned int u32;
typedef __attribute__((ext_vector_type(8))) short short8;
typedef __attribute__((ext_vector_type(4))) float f32x4;
typedef __attribute__((ext_vector_type(2))) float f32x2;

#define BATCH 4
#define NNODE 10000
#define TLEN 128
#define NEDGE 160000
#define GDIM 256
#define NHEAD 4

// fp32 staging offsets for the 20 non-x float inputs (element offsets)
#define O_CW1 0
#define O_CB1 96
#define O_CW2 128
#define O_CB2 6272
#define O_W0  6336
#define O_AS0 22720
#define O_AD0 22976
#define O_B0  23232
#define O_W1  23488
#define O_AS1 89024
#define O_AD1 89280
#define O_B1  89536
#define O_WC1 89792
#define O_BC1 122560
#define O_WC2 122688
#define O_BC2 122944
#define O_WA1 122946
#define O_BA1 139330
#define O_WA2 139394
#define O_BA2 139458
#define W_TOTAL 139459

__device__ __forceinline__ float b2f(bf16 v) { return __bfloat162float(v); }
__device__ __forceinline__ float prelu(float v) { return 0.5f * (v + fabsf(v)); }
__device__ __forceinline__ u16 f2b(float f) {
    union { float f; u32 u; } v; v.f = f;
    u32 r = v.u + 0x7FFF + ((v.u >> 16) & 1);
    return (u16)(r >> 16);
}
__device__ __forceinline__ float u2f(u16 u) {
    union { u32 u; float f; } v; v.u = ((u32)u) << 16;
    return v.f;
}

// per-wave inline dtype probes (all waves compute identical results)
__device__ __forceinline__ bool probe_x_bf16(const void* xsrc) {
    int lane = threadIdx.x & 63;
    u16 h = ((const u16*)xsrc)[2 * lane];
    int e = (h >> 7) & 0xFF;
    unsigned long long m = __ballot(e >= 117 && e <= 130);
    return __popcll(m) >= 32;
}
__device__ __forceinline__ bool probe_ei64(const int* ei) {
    int lane = threadIdx.x & 63;
    int v = ei[2 * lane + 1];
    unsigned long long m = __ballot(v == 0);
    return __popcll(m) >= 56;
}

struct WPtrs { const void* p[20]; };

// ---------------- convert weights to fp32 staging + zero counts/pooled ----------------
#define CVT_WBLK 545
__global__ __launch_bounds__(256) void k_cvt(WPtrs wp, const void* __restrict__ xsrc,
        float* __restrict__ wbuf, int* __restrict__ counts, float* __restrict__ pooled) {
    const int C[21] = {0,96,128,6272,6336,22720,22976,23232,23488,89024,89280,89536,
                       89792,122560,122688,122944,122946,139330,139394,139458,139459};
    bool isbf = probe_x_bf16(xsrc);
    int b = blockIdx.x;
    if (b < CVT_WBLK) {
        int i = b * 256 + threadIdx.x;
        if (i >= W_TOTAL) return;
        int j = 19;
        for (int t = 0; t < 20; ++t) { if (i < C[t + 1]) { j = t; break; } }
        int off = i - C[j];
        const void* sp = wp.p[j];
        wbuf[i] = isbf ? b2f(((const bf16*)sp)[off]) : ((const float*)sp)[off];
    } else {
        int j = (b - CVT_WBLK) * 256 + threadIdx.x;
        if (j < NNODE) counts[j] = 0;
        if (j < BATCH * GDIM) pooled[j] = 0.f;
    }
}

// ---------------- one-time bf16 weight prep + dst histogram (merged) ----------------
__global__ __launch_bounds__(256) void k_prep(const float* __restrict__ wbuf,
        u16* __restrict__ cw2r, u16* __restrict__ W0t, u16* __restrict__ W1t,
        u16* __restrict__ Wa1t, const int* __restrict__ ei, int* __restrict__ counts) {
    bool ei64 = probe_ei64(ei);
    int i = blockIdx.x * 256 + threadIdx.x;
    if (i < 6144) {
        int c2 = i / 96, k = i - c2 * 96, s = k >> 5, ci = k & 31;
        cw2r[i] = f2b(wbuf[O_CW2 + c2 * 96 + ci * 3 + s]);
    }
    if (i < 16384) {
        int c = i >> 6, k = i & 63;
        W0t[c * 64 + k] = f2b(wbuf[O_W0 + k * 256 + c]);
        int ca = i >> 8, ka = i & 255;
        Wa1t[ca * 256 + ka] = f2b(wbuf[O_WA1 + ka * 64 + ca]);
    }
    if (i < 65536) {
        int c = i >> 8, k = i & 255;
        W1t[c * 256 + k] = f2b(wbuf[O_W1 + k * 256 + c]);
    }
    if (i < NEDGE + NNODE) {
        int dst;
        if (i < NEDGE) dst = ei64 ? ei[2 * (NEDGE + i)] : ei[NEDGE + i];
        else dst = i - NEDGE;
        if (dst >= 0 && dst < NNODE) atomicAdd(&counts[dst], 1);
    }
}

// ---------------- parallel scan (3 tiny kernels) ----------------
__global__ __launch_bounds__(256) void k_scan1(const int* __restrict__ counts,
        int* __restrict__ cur, int* __restrict__ bsum) {
    __shared__ int buf[256];
    int tid = threadIdx.x;
    int i = blockIdx.x * 256 + tid;
    int v = (i < NNODE) ? counts[i] : 0;
    buf[tid] = v;
    __syncthreads();
    for (int off = 1; off < 256; off <<= 1) {
        int t = (tid >= off) ? buf[tid - off] : 0;
        __syncthreads();
        buf[tid] += t;
        __syncthreads();
    }
    if (i < NNODE) cur[i] = buf[tid];
    if (tid == 255) bsum[blockIdx.x] = buf[255];
}
__global__ void k_scan2(int* __restrict__ bsum) {
    __shared__ int sb[64];
    int tid = threadIdx.x;
    int v = (tid < 40) ? bsum[tid] : 0;
    sb[tid] = v;
    __syncthreads();
    for (int off = 1; off < 64; off <<= 1) {
        int t = (tid >= off) ? sb[tid - off] : 0;
        __syncthreads();
        sb[tid] += t;
        __syncthreads();
    }
    bsum[64 + tid] = sb[tid] - v;
}
__global__ __launch_bounds__(256) void k_scan3(const int* __restrict__ counts,
        int* __restrict__ cur, const int* __restrict__ bsum, int* __restrict__ row_ptr) {
    int i = blockIdx.x * 256 + threadIdx.x;
    if (i >= NNODE) return;
    int incl = cur[i] + bsum[64 + blockIdx.x];
    row_ptr[i + 1] = incl;
    cur[i] = incl - counts[i];
    if (i == 0) row_ptr[0] = 0;
}

// ---------------- CSR fill ----------------
__global__ void k_fill(const int* __restrict__ ei,
                       int* __restrict__ cur, int* __restrict__ col_src) {
    bool ei64 = probe_ei64(ei);
    int e = blockIdx.x * 256 + threadIdx.x;
    if (e >= NEDGE + NNODE) return;
    int src, dst;
    if (e < NEDGE) {
        if (ei64) { src = ei[2 * e]; dst = ei[2 * (NEDGE + e)]; }
        else      { src = ei[e];     dst = ei[NEDGE + e]; }
    } else {
        src = dst = e - NEDGE;
    }
    if (dst < 0 || dst >= NNODE) return;
    int pos = atomicAdd(&cur[dst], 1);
    if (pos >= 0 && pos < NEDGE + NNODE) col_src[pos] = src;
}

// ---------------- fused temporal conv: WAVE-PER-NODE, barrier-free main loop ----------
#define HSTR 42    // hs row stride u16: 84 B = 21 banks, coprime with 32
#define WSTR 104
__global__ __launch_bounds__(256) void k_conv(const void* __restrict__ xsrc,
        const float* __restrict__ wbuf, const u16* __restrict__ cw2r,
        u16* __restrict__ featb) {
    __shared__ __align__(16) float xs[4][132];
    __shared__ float w1s[96], b1s[32], b2s[64];
    __shared__ __align__(16) u16 w2s[64 * WSTR];
    __shared__ __align__(16) u16 hs[4][66 * HSTR];   // per-wave strip

    bool isbf = probe_x_bf16(xsrc);
    int tid = threadIdx.x;
    int wave = tid >> 6, lane = tid & 63;
    int node = blockIdx.x * 4 + wave;

    // per-wave coalesced x load (2 values per lane)
    {
        int p = lane * 2;
        if (isbf) {
            u32 w = ((const u32*)xsrc)[(size_t)node * 64 + lane];
            xs[wave][1 + p] = u2f((u16)(w & 0xFFFF));
            xs[wave][2 + p] = u2f((u16)(w >> 16));
        } else {
            float2 w = ((const float2*)xsrc)[(size_t)node * 64 + lane];
            xs[wave][1 + p] = w.x;
            xs[wave][2 + p] = w.y;
        }
        if (lane == 0) { xs[wave][0] = 0.f; xs[wave][129] = 0.f; }
        // zero this wave's hs pad rows (t=-1, t=64): 32 channels each
        if (lane < 32) hs[wave][lane] = 0;
        else hs[wave][65 * HSTR + (lane - 32)] = 0;
    }
    if (tid < 96) w1s[tid] = wbuf[O_CW1 + tid];
    if (tid < 32) b1s[tid] = wbuf[O_CB1 + tid];
    if (tid < 64) b2s[tid] = wbuf[O_CB2 + tid];
    for (int i = tid; i < 768; i += 256) {
        int c2 = i / 12, r = i - c2 * 12;
        *(short8*)&w2s[c2 * WSTR + r * 8] = *(const short8*)&cw2r[i * 8];
    }
    __syncthreads();   // the ONLY barrier: w2s/w1s staging

    // conv1 (k=3 same) + relu + maxpool2, this wave's node only
    {
        int d = lane & 15;          // channel pair 2d, 2d+1
        int uu = lane >> 4;         // 0..3
        float wa0 = w1s[6 * d + 0], wa1 = w1s[6 * d + 1], wa2 = w1s[6 * d + 2];
        float wb0 = w1s[6 * d + 3], wb1 = w1s[6 * d + 4], wb2 = w1s[6 * d + 5];
        float ba = b1s[2 * d], bb = b1s[2 * d + 1];
        const float* xr = &xs[wave][0];
        u16* hw = &hs[wave][0];
        #pragma unroll
        for (int it = 0; it < 16; ++it) {
            int u = uu + 4 * it;
            int t0 = 2 * u;
            float x0 = xr[t0], x1 = xr[t0 + 1], x2 = xr[t0 + 2], x3 = xr[t0 + 3];
            f32x2 A = {x0, x1}, Bv = {x1, x2}, Cv = {x2, x3};
            f32x2 va = {ba, ba}; va += wa0 * A; va += wa1 * Bv; va += wa2 * Cv;
            f32x2 vb = {bb, bb}; vb += wb0 * A; vb += wb1 * Bv; vb += wb2 * Cv;
            float ha = fmaxf(fmaxf(va.x, va.y), 0.f);
            float hb = fmaxf(fmaxf(vb.x, vb.y), 0.f);
            u32 pack = (u32)f2b(ha) | ((u32)f2b(hb) << 16);
            *(u32*)&hw[(u + 1) * HSTR + 2 * d] = pack;
        }
    }
    // no barrier: same wave produced hs[wave], lgkmcnt ordering suffices

    // MFMA conv2 over this wave's 4 m-tiles; in-register column reduction
    int m = lane & 15, q = lane >> 4;
    const u16* hw = &hs[wave][0];
    short8 afr[4][3];
    #pragma unroll
    for (int mt = 0; mt < 4; ++mt)
        #pragma unroll
        for (int s = 0; s < 3; ++s)
            afr[mt][s] = *(const short8*)&hw[(mt * 16 + m + s) * HSTR + q * 8];

    float fsum[4];
    #pragma unroll
    for (int nt = 0; nt < 4; ++nt) {
        int n = nt * 16 + m;
        float b2v = b2s[n];
        float scl = 0.f;
        #pragma unroll
        for (int mt = 0; mt < 4; ++mt) {
            f32x4 acc = {0.f, 0.f, 0.f, 0.f};
            #pragma unroll
            for (int s = 0; s < 3; ++s) {
                short8 bfr = *(const short8*)&w2s[n * WSTR + s * 32 + q * 8];
                acc = __builtin_amdgcn_mfma_f32_16x16x32_bf16(afr[mt][s], bfr, acc, 0, 0, 0);
            }
            scl += prelu(acc[0] + b2v) + prelu(acc[1] + b2v)
                 + prelu(acc[2] + b2v) + prelu(acc[3] + b2v);
        }
        scl += __shfl_xor(scl, 16, 64);
        scl += __shfl_xor(scl, 32, 64);
        fsum[nt] = scl;                 // total over t for c2 = nt*16 + m
    }
    if (lane < 16) {
        int bb2 = node / NNODE, nn = node - bb2 * NNODE;
        size_t base = ((size_t)nn * 4 + bb2) * 64;
        #pragma unroll
        for (int nt = 0; nt < 4; ++nt)
            featb[base + nt * 16 + lane] = f2b(fsum[nt] * (1.f / 64.f));
    }
}

// ------ zero-LDS MFMA GEMM with fused attention scores ------
template<int K>
__global__ __launch_bounds__(256) void k_gemm(const u16* __restrict__ A,
        const u16* __restrict__ Wt, const float* __restrict__ att_s_w,
        const float* __restrict__ att_d_w, u16* __restrict__ outb,
        float* __restrict__ a_s, float* __restrict__ a_d) {
    int wave = threadIdx.x >> 6, lane = threadIdx.x & 63;
    int row0 = (blockIdx.x * 4 + wave) * 16;
    int m = lane & 15, q = lane >> 4;
    f32x4 acc[16];
    #pragma unroll
    for (int nt = 0; nt < 16; ++nt) acc[nt] = {0.f, 0.f, 0.f, 0.f};
    for (int kc = 0; kc < K; kc += 32) {
        short8 a = *(const short8*)&A[(size_t)(row0 + m) * K + kc + q * 8];
        #pragma unroll
        for (int nt = 0; nt < 16; ++nt) {
            short8 b = *(const short8*)&Wt[(size_t)(nt * 16 + m) * K + kc + q * 8];
            acc[nt] = __builtin_amdgcn_mfma_f32_16x16x32_bf16(a, b, acc[nt], 0, 0, 0);
        }
    }
    #pragma unroll
    for (int nt = 0; nt < 16; ++nt) {
        #pragma unroll
        for (int r = 0; r < 4; ++r)
            outb[(size_t)(row0 + q * 4 + r) * 256 + nt * 16 + m] = f2b(acc[nt][r]);
    }
    float sh_s[4][4] = {{0}}, sh_d[4][4] = {{0}};
    #pragma unroll
    for (int nt = 0; nt < 16; ++nt) {
        int h = nt >> 2;
        int cc = (nt & 3) * 16 + m;
        float asw = att_s_w[h * 64 + cc];
        float adw = att_d_w[h * 64 + cc];
        #pragma unroll
        for (int r = 0; r < 4; ++r) {
            sh_s[h][r] += acc[nt][r] * asw;
            sh_d[h][r] += acc[nt][r] * adw;
        }
    }
    #pragma unroll
    for (int off = 1; off < 16; off <<= 1) {
        #pragma unroll
        for (int h = 0; h < 4; ++h)
            #pragma unroll
            for (int r = 0; r < 4; ++r) {
                sh_s[h][r] += __shfl_xor(sh_s[h][r], off, 64);
                sh_d[h][r] += __shfl_xor(sh_d[h][r], off, 64);
            }
    }
    if (m == 0) {
        #pragma unroll
        for (int r = 0; r < 4; ++r) {
            int row = row0 + q * 4 + r;
            float4 vs = {sh_s[0][r], sh_s[1][r], sh_s[2][r], sh_s[3][r]};
            float4 vd = {sh_d[0][r], sh_d[1][r], sh_d[2][r], sh_d[3][r]};
            *(float4*)&a_s[(size_t)row * 4] = vs;
            *(float4*)&a_d[(size_t)row * 4] = vd;
        }
    }
}

// ---------------- GAT aggregation: wave per dst, lane owns 16 ch of 1 head;
// pass-2 software-pipelined gather ----------------
__global__ __launch_bounds__(256) void k_agg(const u16* __restrict__ xlb,
        const float* __restrict__ a_s, const float* __restrict__ a_d,
        const int* __restrict__ row_ptr, const int* __restrict__ col_src,
        const float* __restrict__ bias, u16* __restrict__ gb_out) {
    int dst = blockIdx.x * 4 + (threadIdx.x >> 6);
    int lane = threadIdx.x & 63;
    int b = lane >> 4, s = lane & 15;
    int h = s >> 2;
    int beg = row_ptr[dst], end = row_ptr[dst + 1];

    // pass 1: exact max; edges split 4-way across replica groups
    int bh = lane & 15;
    float adv1 = a_d[(size_t)dst * 16 + bh];
    float mloc = -INFINITY;
    for (int i = beg + b; i < end; i += 4) {
        int src = col_src[i];
        src = min(max(src, 0), NNODE - 1);
        float e = a_s[(size_t)src * 16 + bh] + adv1;
        e = (e >= 0.f) ? e : 0.2f * e;
        mloc = fmaxf(mloc, e);
    }
    mloc = fmaxf(mloc, __shfl_xor(mloc, 16, 64));
    mloc = fmaxf(mloc, __shfl_xor(mloc, 32, 64));
    float mv = __shfl(mloc, b * 4 + h, 64);

    // pass 2: one-edge-ahead prefetch pipeline
    float advh = a_d[(size_t)dst * 16 + b * 4 + h];
    float acc[16];
    #pragma unroll
    for (int k = 0; k < 16; ++k) acc[k] = 0.f;
    float l = 0.f;

    int i = beg;
    int src_c = 0; float as_c = 0.f; short8 x0_c = {0}, x1_c = {0};
    if (i < end) {
        src_c = min(max(col_src[i], 0), NNODE - 1);
        as_c = a_s[(size_t)src_c * 16 + b * 4 + h];
        size_t xb = ((size_t)src_c * 4 + b) * 256 + s * 16;
        x0_c = *(const short8*)&xlb[xb];
        x1_c = *(const short8*)&xlb[xb + 8];
    }
    while (i < end) {
        int inext = i + 1;
        int src_n = 0; float as_n = 0.f; short8 x0_n = {0}, x1_n = {0};
        if (inext < end) {
            src_n = min(max(col_src[inext], 0), NNODE - 1);
            as_n = a_s[(size_t)src_n * 16 + b * 4 + h];
            size_t xb = ((size_t)src_n * 4 + b) * 256 + s * 16;
            x0_n = *(const short8*)&xlb[xb];
            x1_n = *(const short8*)&xlb[xb + 8];
        }
        float e = as_c + advh;
        e = (e >= 0.f) ? e : 0.2f * e;
        float p = __expf(e - mv);
        l += p;
        #pragma unroll
        for (int k = 0; k < 8; ++k) acc[k] += p * u2f((u16)x0_c[k]);
        #pragma unroll
        for (int k = 0; k < 8; ++k) acc[k + 8] += p * u2f((u16)x1_c[k]);
        src_c = src_n; as_c = as_n; x0_c = x0_n; x1_c = x1_n;
        i = inext;
    }
    float rl = 1.f / (l + 1e-16f);
    size_t ob = ((size_t)dst * 4 + b) * 256 + s * 16;
    short8 o0, o1;
    #pragma unroll
    for (int k = 0; k < 8; ++k) {
        o0[k] = (short)f2b(prelu(acc[k] * rl + bias[s * 16 + k]));
        o1[k] = (short)f2b(prelu(acc[k + 8] * rl + bias[s * 16 + 8 + k]));
    }
    *(short8*)&gb_out[ob] = o0;
    *(short8*)&gb_out[ob + 8] = o1;
}

// ---------------- pooled sum from bf16 g ----------------
__global__ __launch_bounds__(256) void k_pool(const u16* __restrict__ g,
                                              float* __restrict__ pooled) {
    int b = blockIdx.x >> 6;
    int chunk = blockIdx.x & 63;
    int c = threadIdx.x;
    int n0 = chunk * 157;
    int n1 = min(NNODE, n0 + 157);
    float acc = 0.f;
    for (int n = n0; n < n1; ++n)
        acc += u2f(g[((size_t)n * 4 + b) * 256 + c]);
    atomicAdd(&pooled[b * 256 + c], acc);
}

// ---------------- classification head: one block per batch ----------------
__global__ __launch_bounds__(128) void k_logits(const float* __restrict__ pooled,
        const float* __restrict__ wbuf, float* __restrict__ out) {
    __shared__ float pm[256];
    __shared__ float red[4];
    int b = blockIdx.x;
    int tid = threadIdx.x;
    pm[tid] = pooled[b * 256 + tid] * (1.f / NNODE);
    pm[tid + 128] = pooled[b * 256 + tid + 128] * (1.f / NNODE);
    __syncthreads();
    float acc = wbuf[O_BC1 + tid];
    #pragma unroll 4
    for (int k = 0; k < 256; ++k)
        acc += pm[k] * wbuf[O_WC1 + k * 128 + tid];
    float hv = prelu(acc);
    float p0 = hv * wbuf[O_WC2 + tid * 2];
    float p1 = hv * wbuf[O_WC2 + tid * 2 + 1];
    #pragma unroll
    for (int off = 32; off > 0; off >>= 1) {
        p0 += __shfl_xor(p0, off, 64);
        p1 += __shfl_xor(p1, off, 64);
    }
    int wv = tid >> 6, lane = tid & 63;
    if (lane == 0) { red[wv * 2] = p0; red[wv * 2 + 1] = p1; }
    __syncthreads();
    if (tid < 2)
        out[b * 2 + tid] = red[tid] + red[2 + tid] + wbuf[O_BC2 + tid];
}

// ---------------- attribution head: MFMA 40000x64x256 + fused relu.Wa2 dot ----------
__global__ __launch_bounds__(256) void k_attr(const u16* __restrict__ gb,
        const u16* __restrict__ Wa1t, const float* __restrict__ wbuf,
        float* __restrict__ out) {
    int wave = threadIdx.x >> 6, lane = threadIdx.x & 63;
    int row0 = (blockIdx.x * 4 + wave) * 16;
    int m = lane & 15, q = lane >> 4;
    f32x4 acc[4];
    #pragma unroll
    for (int nt = 0; nt < 4; ++nt) acc[nt] = {0.f, 0.f, 0.f, 0.f};
    for (int kc = 0; kc < 256; kc += 32) {
        short8 a = *(const short8*)&gb[(size_t)(row0 + m) * 256 + kc + q * 8];
        #pragma unroll
        for (int nt = 0; nt < 4; ++nt) {
            short8 b = *(const short8*)&Wa1t[(size_t)(nt * 16 + m) * 256 + kc + q * 8];
            acc[nt] = __builtin_amdgcn_mfma_f32_16x16x32_bf16(a, b, acc[nt], 0, 0, 0);
        }
    }
    float part[4] = {0, 0, 0, 0};
    #pragma unroll
    for (int nt = 0; nt < 4; ++nt) {
        int col = nt * 16 + m;
        float ba1v = wbuf[O_BA1 + col];
        float wa2v = wbuf[O_WA2 + col];
        #pragma unroll
        for (int r = 0; r < 4; ++r)
            part[r] += prelu(acc[nt][r] + ba1v) * wa2v;
    }
    #pragma unroll
    for (int off = 1; off < 16; off <<= 1) {
        #pragma unroll
        for (int r = 0; r < 4; ++r)
            part[r] += __shfl_xor(part[r], off, 64);
    }
    if (m == 0) {
        float ba2v = wbuf[O_BA2];
        #pragma unroll
        for (int r = 0; r < 4; ++r) {
            int row = row0 + q * 4 + r;
            int n = row >> 2, b = row & 3;
            float v = part[r] + ba2v;
            out[8 + b * NNODE + n] = 1.f / (1.f + __expf(-v));
        }
    }
}

// ---------------- diagnostics (sampled) ----------------
__global__ __launch_bounds__(256) void k_diag(float* __restrict__ out,
        const u16* __restrict__ featb, const u16* __restrict__ gb,
        const int* __restrict__ row_ptr, const int* __restrict__ ei,
        const void* __restrict__ xsrc, int hostbad) {
    __shared__ float red[256];
    bool ei64 = probe_ei64(ei);
    bool isbf = probe_x_bf16(xsrc);
    int tid = threadIdx.x;
    float mx[2] = {0.f, 0.f};
    const u16* bufs[2] = {featb, gb};
    for (int q = 0; q < 2; ++q) {
        const u16* p = bufs[q];
        float m = 0.f;
        for (int i = tid; i < 2048; i += 256) {
            float v = u2f(p[i]);
            if (v != v) m = 1e30f;
            m = fmaxf(m, fabsf(v));
        }
        red[tid] = m;
        __syncthreads();
        for (int s2 = 128; s2 > 0; s2 >>= 1) {
            if (tid < s2) red[tid] = fmaxf(red[tid], red[tid + s2]);
            __syncthreads();
        }
        mx[q] = red[0];
        __syncthreads();
    }
    if (tid == 0) {
        int fb = (mx[0] > 1e8f || mx[0] < 1e-6f) ? 1 : 0;
        int gbad = (mx[1] > 1e8f || mx[1] < 1e-6f) ? 1 : 0;
        int cb = (row_ptr[NNODE] != NEDGE + NNODE) ? 1 : 0;
        int code = 100 * fb + 400 * gbad + 800 * cb + 6400 * hostbad;
        if (code) {
            code += 1600 * (isbf ? 0 : 1);
            code += 3200 * (ei64 ? 1 : 0);
            for (int j = 0; j < 8; ++j) out[j] = (float)code;
        }
    }
}

extern "C" void kernel_launch(void* const* d_in, const int* in_sizes, int n_in,
                              void* d_out, int out_size, void* d_ws, size_t ws_size,
                              hipStream_t stream) {
    const void* x  = d_in[0];
    const int*  ei = (const int*)d_in[1];
    float* out = (float*)d_out;

    WPtrs wp;
    for (int j = 0; j < 20; ++j) wp.p[j] = d_in[j + 2];

    char* ws = (char*)d_ws;
    size_t off = 0;
    auto alloc = [&](size_t bytes) -> void* {
        void* p = ws + off;
        off += (bytes + 255) & ~(size_t)255;
        return p;
    };
    float* wbuf    = (float*)alloc((size_t)W_TOTAL * 4);
    u16*   featb   = (u16*)  alloc((size_t)BATCH * NNODE * 64 * 2);
    u16*   xlb     = (u16*)  alloc((size_t)BATCH * NNODE * 256 * 2);
    u16*   gb      = (u16*)  alloc((size_t)BATCH * NNODE * 256 * 2);
    float* a_s     = (float*)alloc((size_t)BATCH * NNODE * 4 * 4);
    float* a_d     = (float*)alloc((size_t)BATCH * NNODE * 4 * 4);
    float* pooled  = (float*)alloc(BATCH * 256 * 4);
    u16*   cw2r    = (u16*)alloc(6144 * 2);
    u16*   W0t     = (u16*)alloc(16384 * 2);
    u16*   W1t     = (u16*)alloc(65536 * 2);
    u16*   Wa1t    = (u16*)alloc(16384 * 2);
    int*   counts  = (int*)alloc(NNODE * 4);
    int*   row_ptr = (int*)alloc((NNODE + 1) * 4);
    int*   cur     = (int*)alloc(NNODE * 4);
    int*   col_src = (int*)alloc((NEDGE + NNODE) * 4);
    int*   bsum    = (int*)alloc(128 * 4);
    (void)ws_size; (void)out_size;

    int hostbad = (n_in != 22 || in_sizes[0] != BATCH * NNODE * TLEN ||
                   in_sizes[1] != 2 * NEDGE) ? 1 : 0;

    int eg = (NEDGE + NNODE + 255) / 256;

    k_cvt<<<CVT_WBLK + 40, 256, 0, stream>>>(wp, x, wbuf, counts, pooled);
    k_prep<<<eg, 256, 0, stream>>>(wbuf, cw2r, W0t, W1t, Wa1t, ei, counts);
    k_scan1<<<40, 256, 0, stream>>>(counts, cur, bsum);
    k_scan2<<<1, 64, 0, stream>>>(bsum);
    k_scan3<<<40, 256, 0, stream>>>(counts, cur, bsum, row_ptr);
    k_fill<<<eg, 256, 0, stream>>>(ei, cur, col_src);

    k_conv<<<BATCH * NNODE / 4, 256, 0, stream>>>(x, wbuf, cw2r, featb);

    // GAT layer 0 (attention scores fused into GEMM epilogue)
    k_gemm<64><<<BATCH * NNODE / 64, 256, 0, stream>>>(featb, W0t,
            wbuf + O_AS0, wbuf + O_AD0, xlb, a_s, a_d);
    k_agg<<<NNODE / 4, 256, 0, stream>>>(xlb, a_s, a_d, row_ptr, col_src, wbuf + O_B0, gb);

    // GAT layer 1
    k_gemm<256><<<BATCH * NNODE / 64, 256, 0, stream>>>(gb, W1t,
            wbuf + O_AS1, wbuf + O_AD1, xlb, a_s, a_d);
    k_agg<<<NNODE / 4, 256, 0, stream>>>(xlb, a_s, a_d, row_ptr, col_src, wbuf + O_B1, gb);

    // heads
    k_pool<<<BATCH * 64, 256, 0, stream>>>(gb, pooled);
    k_logits<<<4, 128, 0, stream>>>(pooled, wbuf, out);
    k_attr<<<BATCH * NNODE / 64, 256, 0, stream>>>(gb, Wa1t, wbuf, out);

    k_diag<<<1, 256, 0, stream>>>(out, featb, gb, row_ptr, ei, x, hostbad);
}

// Round 10
// 491.833 us; speedup vs baseline: 1.0220x; 1.0220x over previous
//
#include <hip/hip_runtime.h>
#include <hip/hip_bf16.h>
#include <math.h>

typedef __hip_bfloat16 bf16;
typedef unsigned short u16;
typedef unsigned int u32;
typedef __attribute__((ext_vector_type(8))) short short8;
typedef __attribute__((ext_vector_type(4))) float f32x4;
typedef __attribute__((ext_vector_type(2))) float f32x2;

#define BATCH 4
#define NNODE 10000
#define TLEN 128
#define NEDGE 160000
#define GDIM 256
#define NHEAD 4

// fp32 staging offsets for the 20 non-x float inputs (element offsets)
#define O_CW1 0
#define O_CB1 96
#define O_CW2 128
#define O_CB2 6272
#define O_W0  6336
#define O_AS0 22720
#define O_AD0 22976
#define O_B0  23232
#define O_W1  23488
#define O_AS1 89024
#define O_AD1 89280
#define O_B1  89536
#define O_WC1 89792
#define O_BC1 122560
#define O_WC2 122688
#define O_BC2 122944
#define O_WA1 122946
#define O_BA1 139330
#define O_WA2 139394
#define O_BA2 139458
#define W_TOTAL 139459

__device__ __forceinline__ float b2f(bf16 v) { return __bfloat162float(v); }
__device__ __forceinline__ float prelu(float v) { return 0.5f * (v + fabsf(v)); }
__device__ __forceinline__ u16 f2b(float f) {
    union { float f; u32 u; } v; v.f = f;
    u32 r = v.u + 0x7FFF + ((v.u >> 16) & 1);
    return (u16)(r >> 16);
}
__device__ __forceinline__ float u2f(u16 u) {
    union { u32 u; float f; } v; v.u = ((u32)u) << 16;
    return v.f;
}

// per-wave inline dtype probes (all waves compute identical results)
__device__ __forceinline__ bool probe_x_bf16(const void* xsrc) {
    int lane = threadIdx.x & 63;
    u16 h = ((const u16*)xsrc)[2 * lane];
    int e = (h >> 7) & 0xFF;
    unsigned long long m = __ballot(e >= 117 && e <= 130);
    return __popcll(m) >= 32;
}
__device__ __forceinline__ bool probe_ei64(const int* ei) {
    int lane = threadIdx.x & 63;
    int v = ei[2 * lane + 1];
    unsigned long long m = __ballot(v == 0);
    return __popcll(m) >= 56;
}

struct WPtrs { const void* p[20]; };

// ---------------- convert weights to fp32 staging + zero counts/pooled ----------------
#define CVT_WBLK 545
__global__ __launch_bounds__(256) void k_cvt(WPtrs wp, const void* __restrict__ xsrc,
        float* __restrict__ wbuf, int* __restrict__ counts, float* __restrict__ pooled) {
    const int C[21] = {0,96,128,6272,6336,22720,22976,23232,23488,89024,89280,89536,
                       89792,122560,122688,122944,122946,139330,139394,139458,139459};
    bool isbf = probe_x_bf16(xsrc);
    int b = blockIdx.x;
    if (b < CVT_WBLK) {
        int i = b * 256 + threadIdx.x;
        if (i >= W_TOTAL) return;
        int j = 19;
        for (int t = 0; t < 20; ++t) { if (i < C[t + 1]) { j = t; break; } }
        int off = i - C[j];
        const void* sp = wp.p[j];
        wbuf[i] = isbf ? b2f(((const bf16*)sp)[off]) : ((const float*)sp)[off];
    } else {
        int j = (b - CVT_WBLK) * 256 + threadIdx.x;
        if (j < NNODE) counts[j] = 0;
        if (j < BATCH * GDIM) pooled[j] = 0.f;
    }
}

// ---------------- one-time bf16 weight prep + dst histogram (merged) ----------------
// transposes: coalesced READS, scattered writes (stores don't stall)
__global__ __launch_bounds__(256) void k_prep(const float* __restrict__ wbuf,
        u16* __restrict__ cw2r, u16* __restrict__ W0t, u16* __restrict__ W1t,
        u16* __restrict__ Wa1t, const int* __restrict__ ei, int* __restrict__ counts) {
    bool ei64 = probe_ei64(ei);
    int i = blockIdx.x * 256 + threadIdx.x;
    if (i < 6144) {
        int c2 = i / 96, k = i - c2 * 96, s = k >> 5, ci = k & 31;
        cw2r[i] = f2b(wbuf[O_CW2 + c2 * 96 + ci * 3 + s]);
    }
    if (i < 16384) {
        int k = i >> 8, c = i & 255;            // read W0[k][c] coalesced
        W0t[c * 64 + k] = f2b(wbuf[O_W0 + k * 256 + c]);
        int ka = i >> 6, ca = i & 63;           // read Wa1[ka][ca] coalesced
        Wa1t[ca * 256 + ka] = f2b(wbuf[O_WA1 + ka * 64 + ca]);
    }
    if (i < 65536) {
        int k = i >> 8, c = i & 255;            // read W1[k][c] coalesced
        W1t[c * 256 + k] = f2b(wbuf[O_W1 + k * 256 + c]);
    }
    if (i < NEDGE + NNODE) {
        int dst;
        if (i < NEDGE) dst = ei64 ? ei[2 * (NEDGE + i)] : ei[NEDGE + i];
        else dst = i - NEDGE;
        if (dst >= 0 && dst < NNODE) atomicAdd(&counts[dst], 1);
    }
}

// ---------------- parallel scan (3 tiny kernels) ----------------
__global__ __launch_bounds__(256) void k_scan1(const int* __restrict__ counts,
        int* __restrict__ cur, int* __restrict__ bsum) {
    __shared__ int buf[256];
    int tid = threadIdx.x;
    int i = blockIdx.x * 256 + tid;
    int v = (i < NNODE) ? counts[i] : 0;
    buf[tid] = v;
    __syncthreads();
    for (int off = 1; off < 256; off <<= 1) {
        int t = (tid >= off) ? buf[tid - off] : 0;
        __syncthreads();
        buf[tid] += t;
        __syncthreads();
    }
    if (i < NNODE) cur[i] = buf[tid];
    if (tid == 255) bsum[blockIdx.x] = buf[255];
}
__global__ void k_scan2(int* __restrict__ bsum) {
    __shared__ int sb[64];
    int tid = threadIdx.x;
    int v = (tid < 40) ? bsum[tid] : 0;
    sb[tid] = v;
    __syncthreads();
    for (int off = 1; off < 64; off <<= 1) {
        int t = (tid >= off) ? sb[tid - off] : 0;
        __syncthreads();
        sb[tid] += t;
        __syncthreads();
    }
    bsum[64 + tid] = sb[tid] - v;
}
__global__ __launch_bounds__(256) void k_scan3(const int* __restrict__ counts,
        int* __restrict__ cur, const int* __restrict__ bsum, int* __restrict__ row_ptr) {
    int i = blockIdx.x * 256 + threadIdx.x;
    if (i >= NNODE) return;
    int incl = cur[i] + bsum[64 + blockIdx.x];
    row_ptr[i + 1] = incl;
    cur[i] = incl - counts[i];
    if (i == 0) row_ptr[0] = 0;
}

// ---------------- CSR fill ----------------
__global__ void k_fill(const int* __restrict__ ei,
                       int* __restrict__ cur, int* __restrict__ col_src) {
    bool ei64 = probe_ei64(ei);
    int e = blockIdx.x * 256 + threadIdx.x;
    if (e >= NEDGE + NNODE) return;
    int src, dst;
    if (e < NEDGE) {
        if (ei64) { src = ei[2 * e]; dst = ei[2 * (NEDGE + e)]; }
        else      { src = ei[e];     dst = ei[NEDGE + e]; }
    } else {
        src = dst = e - NEDGE;
    }
    if (dst < 0 || dst >= NNODE) return;
    int pos = atomicAdd(&cur[dst], 1);
    if (pos >= 0 && pos < NEDGE + NNODE) col_src[pos] = src;
}

// ---------------- fused temporal conv: R8 structure (4 nodes/block, shared hs), HSTR 42 --
#define HSTR 42    // hs row stride u16: 84 B = 21 dwords, coprime with 32 banks
#define WSTR 104
__global__ __launch_bounds__(256) void k_conv(const void* __restrict__ xsrc,
        const float* __restrict__ wbuf, const u16* __restrict__ cw2r,
        u16* __restrict__ featb) {
    __shared__ __align__(16) float xs[4][132];
    __shared__ float w1s[96], b1s[32], b2s[64];
    __shared__ __align__(16) u16 w2s[64 * WSTR];
    __shared__ __align__(16) u16 hs[66 * HSTR];
    __shared__ float red2[4][64];

    bool isbf = probe_x_bf16(xsrc);
    int tid = threadIdx.x;
    int wave = tid >> 6, lane = tid & 63;
    int node0 = blockIdx.x * 4;

    {
        int j = tid >> 6, p = (tid & 63) * 2;
        if (isbf) {
            u32 w = ((const u32*)xsrc)[(size_t)node0 * 64 + tid];
            xs[j][1 + p] = u2f((u16)(w & 0xFFFF));
            xs[j][2 + p] = u2f((u16)(w >> 16));
        } else {
            float2 w = ((const float2*)xsrc)[(size_t)node0 * 64 + tid];
            xs[j][1 + p] = w.x;
            xs[j][2 + p] = w.y;
        }
    }
    if (tid < 8) xs[tid >> 1][(tid & 1) ? 129 : 0] = 0.f;
    if (tid < 96) w1s[tid] = wbuf[O_CW1 + tid];
    if (tid < 32) b1s[tid] = wbuf[O_CB1 + tid];
    if (tid < 64) b2s[tid] = wbuf[O_CB2 + tid];
    for (int i = tid; i < 768; i += 256) {
        int c2 = i / 12, r = i - c2 * 12;
        *(short8*)&w2s[c2 * WSTR + r * 8] = *(const short8*)&cw2r[i * 8];
    }
    if (tid < 32) hs[tid] = 0;
    else if (tid < 64) hs[65 * HSTR + (tid - 32)] = 0;
    __syncthreads();

    int d = tid & 15, uu = tid >> 4;
    float wa0 = w1s[6 * d + 0], wa1 = w1s[6 * d + 1], wa2 = w1s[6 * d + 2];
    float wb0 = w1s[6 * d + 3], wb1 = w1s[6 * d + 4], wb2 = w1s[6 * d + 5];
    float ba = b1s[2 * d], bb = b1s[2 * d + 1];
    int m = lane & 15, q = lane >> 4;
    int trow = wave * 16 + m;

    for (int j = 0; j < 4; ++j) {
        const float* xr = &xs[j][0];
        #pragma unroll
        for (int it = 0; it < 4; ++it) {
            int u = uu + 16 * it;
            int t0 = 2 * u;
            float x0 = xr[t0], x1 = xr[t0 + 1], x2 = xr[t0 + 2], x3 = xr[t0 + 3];
            f32x2 A = {x0, x1}, Bv = {x1, x2}, Cv = {x2, x3};
            f32x2 va = {ba, ba}; va += wa0 * A; va += wa1 * Bv; va += wa2 * Cv;
            f32x2 vb = {bb, bb}; vb += wb0 * A; vb += wb1 * Bv; vb += wb2 * Cv;
            float ha = fmaxf(fmaxf(va.x, va.y), 0.f);
            float hb = fmaxf(fmaxf(vb.x, vb.y), 0.f);
            u32 pack = (u32)f2b(ha) | ((u32)f2b(hb) << 16);
            *(u32*)&hs[(u + 1) * HSTR + 2 * d] = pack;
        }
        __syncthreads();

        short8 afr[3];
        #pragma unroll
        for (int s = 0; s < 3; ++s)
            afr[s] = *(const short8*)&hs[(trow + s) * HSTR + q * 8];
        float psum[4];
        #pragma unroll
        for (int nt = 0; nt < 4; ++nt) {
            int n = nt * 16 + m;
            f32x4 acc = {0.f, 0.f, 0.f, 0.f};
            #pragma unroll
            for (int s = 0; s < 3; ++s) {
                short8 bfr = *(const short8*)&w2s[n * WSTR + s * 32 + q * 8];
                acc = __builtin_amdgcn_mfma_f32_16x16x32_bf16(afr[s], bfr, acc, 0, 0, 0);
            }
            float b2v = b2s[n];
            float scl = prelu(acc[0] + b2v) + prelu(acc[1] + b2v)
                      + prelu(acc[2] + b2v) + prelu(acc[3] + b2v);
            scl += __shfl_xor(scl, 16, 64);
            scl += __shfl_xor(scl, 32, 64);
            psum[nt] = scl;
        }
        if (lane < 16) {
            #pragma unroll
            for (int nt = 0; nt < 4; ++nt)
                red2[wave][nt * 16 + lane] = psum[nt];
        }
        __syncthreads();
        if (tid < 64) {
            float tot = (red2[0][tid] + red2[1][tid] + red2[2][tid] + red2[3][tid]) * (1.f / 64.f);
            int node = node0 + j;
            int bb2 = node / NNODE, nn = node - bb2 * NNODE;
            featb[((size_t)nn * 4 + bb2) * 64 + tid] = f2b(tot);
        }
    }
}

// ------ zero-LDS MFMA GEMM, MT m-tiles per wave, fused attention scores ------
template<int K, int MT>
__global__ __launch_bounds__(256) void k_gemm(const u16* __restrict__ A,
        const u16* __restrict__ Wt, const float* __restrict__ att_s_w,
        const float* __restrict__ att_d_w, u16* __restrict__ outb,
        float* __restrict__ a_s, float* __restrict__ a_d) {
    int wave = threadIdx.x >> 6, lane = threadIdx.x & 63;
    int row0 = (blockIdx.x * 4 + wave) * 16 * MT;
    if (row0 >= BATCH * NNODE) return;
    int m = lane & 15, q = lane >> 4;
    f32x4 acc[MT][16];
    #pragma unroll
    for (int mt = 0; mt < MT; ++mt)
        #pragma unroll
        for (int nt = 0; nt < 16; ++nt) acc[mt][nt] = {0.f, 0.f, 0.f, 0.f};
    for (int kc = 0; kc < K; kc += 32) {
        short8 a[MT];
        #pragma unroll
        for (int mt = 0; mt < MT; ++mt)
            a[mt] = *(const short8*)&A[(size_t)(row0 + mt * 16 + m) * K + kc + q * 8];
        #pragma unroll
        for (int nt = 0; nt < 16; ++nt) {
            short8 b = *(const short8*)&Wt[(size_t)(nt * 16 + m) * K + kc + q * 8];
            #pragma unroll
            for (int mt = 0; mt < MT; ++mt)
                acc[mt][nt] = __builtin_amdgcn_mfma_f32_16x16x32_bf16(a[mt], b, acc[mt][nt], 0, 0, 0);
        }
    }
    #pragma unroll
    for (int mt = 0; mt < MT; ++mt) {
        int r0 = row0 + mt * 16;
        #pragma unroll
        for (int nt = 0; nt < 16; ++nt) {
            #pragma unroll
            for (int r = 0; r < 4; ++r)
                outb[(size_t)(r0 + q * 4 + r) * 256 + nt * 16 + m] = f2b(acc[mt][nt][r]);
        }
        float sh_s[4][4] = {{0}}, sh_d[4][4] = {{0}};
        #pragma unroll
        for (int nt = 0; nt < 16; ++nt) {
            int h = nt >> 2;
            int cc = (nt & 3) * 16 + m;
            float asw = att_s_w[h * 64 + cc];
            float adw = att_d_w[h * 64 + cc];
            #pragma unroll
            for (int r = 0; r < 4; ++r) {
                sh_s[h][r] += acc[mt][nt][r] * asw;
                sh_d[h][r] += acc[mt][nt][r] * adw;
            }
        }
        #pragma unroll
        for (int off = 1; off < 16; off <<= 1) {
            #pragma unroll
            for (int h = 0; h < 4; ++h)
                #pragma unroll
                for (int r = 0; r < 4; ++r) {
                    sh_s[h][r] += __shfl_xor(sh_s[h][r], off, 64);
                    sh_d[h][r] += __shfl_xor(sh_d[h][r], off, 64);
                }
        }
        if (m == 0) {
            #pragma unroll
            for (int r = 0; r < 4; ++r) {
                int row = r0 + q * 4 + r;
                float4 vs = {sh_s[0][r], sh_s[1][r], sh_s[2][r], sh_s[3][r]};
                float4 vd = {sh_d[0][r], sh_d[1][r], sh_d[2][r], sh_d[3][r]};
                *(float4*)&a_s[(size_t)row * 4] = vs;
                *(float4*)&a_d[(size_t)row * 4] = vd;
            }
        }
    }
}

// ---------------- GAT aggregation: 2 dst/block, wave owns 2 batches;
// lane owns 8 channels of one (b,h); pass-2 prefetch pipeline ----------------
__global__ __launch_bounds__(256) void k_agg(const u16* __restrict__ xlb,
        const float* __restrict__ a_s, const float* __restrict__ a_d,
        const int* __restrict__ row_ptr, const int* __restrict__ col_src,
        const float* __restrict__ bias, u16* __restrict__ gb_out) {
    int wave = threadIdx.x >> 6, lane = threadIdx.x & 63;
    int dst = blockIdx.x * 2 + (wave >> 1);
    int bp = (wave & 1) * 2;               // this wave's batch pair
    int beg = row_ptr[dst], end = row_ptr[dst + 1];

    // pass 1: exact max per (b,h); 8-way edge split across replica groups
    int c = lane & 7, g = lane >> 3;       // combo c = bl*4+h, group g
    int bc = bp + (c >> 2), hc = c & 3;
    float adv1 = a_d[(size_t)dst * 16 + bc * 4 + hc];
    float mloc = -INFINITY;
    for (int i = beg + g; i < end; i += 8) {
        int src = min(max(col_src[i], 0), NNODE - 1);
        float e = a_s[(size_t)src * 16 + bc * 4 + hc] + adv1;
        e = (e >= 0.f) ? e : 0.2f * e;
        mloc = fmaxf(mloc, e);
    }
    mloc = fmaxf(mloc, __shfl_xor(mloc, 8, 64));
    mloc = fmaxf(mloc, __shfl_xor(mloc, 16, 64));
    mloc = fmaxf(mloc, __shfl_xor(mloc, 32, 64));

    int bl = lane >> 5;                    // 0/1 within wave
    int s = lane & 31;                     // channel block: s*8 .. s*8+7
    int h = s >> 3;
    int b = bp + bl;
    float mv = __shfl(mloc, bl * 4 + h, 64);

    // pass 2: one-edge-ahead prefetch; 1 exp + 1x16B gather + 8 FMAs per edge
    float advh = a_d[(size_t)dst * 16 + b * 4 + h];
    float acc[8];
    #pragma unroll
    for (int k = 0; k < 8; ++k) acc[k] = 0.f;
    float l = 0.f;

    int i = beg;
    float as_c = 0.f; short8 x_c = {0};
    if (i < end) {
        int src = min(max(col_src[i], 0), NNODE - 1);
        as_c = a_s[(size_t)src * 16 + b * 4 + h];
        x_c = *(const short8*)&xlb[((size_t)src * 4 + b) * 256 + s * 8];
    }
    while (i < end) {
        int inext = i + 1;
        float as_n = 0.f; short8 x_n = {0};
        if (inext < end) {
            int src = min(max(col_src[inext], 0), NNODE - 1);
            as_n = a_s[(size_t)src * 16 + b * 4 + h];
            x_n = *(const short8*)&xlb[((size_t)src * 4 + b) * 256 + s * 8];
        }
        float e = as_c + advh;
        e = (e >= 0.f) ? e : 0.2f * e;
        float p = __expf(e - mv);
        l += p;
        #pragma unroll
        for (int k = 0; k < 8; ++k) acc[k] += p * u2f((u16)x_c[k]);
        as_c = as_n; x_c = x_n;
        i = inext;
    }
    float rl = 1.f / (l + 1e-16f);
    short8 o;
    #pragma unroll
    for (int k = 0; k < 8; ++k)
        o[k] = (short)f2b(prelu(acc[k] * rl + bias[s * 8 + k]));
    *(short8*)&gb_out[((size_t)dst * 4 + b) * 256 + s * 8] = o;
}

// ---------------- pooled sum from bf16 g ----------------
__global__ __launch_bounds__(256) void k_pool(const u16* __restrict__ g,
                                              float* __restrict__ pooled) {
    int b = blockIdx.x >> 6;
    int chunk = blockIdx.x & 63;
    int c = threadIdx.x;
    int n0 = chunk * 157;
    int n1 = min(NNODE, n0 + 157);
    float acc = 0.f;
    for (int n = n0; n < n1; ++n)
        acc += u2f(g[((size_t)n * 4 + b) * 256 + c]);
    atomicAdd(&pooled[b * 256 + c], acc);
}

// ---------------- classification head: one block per batch ----------------
__global__ __launch_bounds__(128) void k_logits(const float* __restrict__ pooled,
        const float* __restrict__ wbuf, float* __restrict__ out) {
    __shared__ float pm[256];
    __shared__ float red[4];
    int b = blockIdx.x;
    int tid = threadIdx.x;
    pm[tid] = pooled[b * 256 + tid] * (1.f / NNODE);
    pm[tid + 128] = pooled[b * 256 + tid + 128] * (1.f / NNODE);
    __syncthreads();
    float acc = wbuf[O_BC1 + tid];
    #pragma unroll 4
    for (int k = 0; k < 256; ++k)
        acc += pm[k] * wbuf[O_WC1 + k * 128 + tid];
    float hv = prelu(acc);
    float p0 = hv * wbuf[O_WC2 + tid * 2];
    float p1 = hv * wbuf[O_WC2 + tid * 2 + 1];
    #pragma unroll
    for (int off = 32; off > 0; off >>= 1) {
        p0 += __shfl_xor(p0, off, 64);
        p1 += __shfl_xor(p1, off, 64);
    }
    int wv = tid >> 6, lane = tid & 63;
    if (lane == 0) { red[wv * 2] = p0; red[wv * 2 + 1] = p1; }
    __syncthreads();
    if (tid < 2)
        out[b * 2 + tid] = red[tid] + red[2 + tid] + wbuf[O_BC2 + tid];
}

// ---------------- attribution head: MFMA 40000x64x256 + fused relu.Wa2 dot ----------
__global__ __launch_bounds__(256) void k_attr(const u16* __restrict__ gb,
        const u16* __restrict__ Wa1t, const float* __restrict__ wbuf,
        float* __restrict__ out) {
    int wave = threadIdx.x >> 6, lane = threadIdx.x & 63;
    int row0 = (blockIdx.x * 4 + wave) * 16;
    int m = lane & 15, q = lane >> 4;
    f32x4 acc[4];
    #pragma unroll
    for (int nt = 0; nt < 4; ++nt) acc[nt] = {0.f, 0.f, 0.f, 0.f};
    for (int kc = 0; kc < 256; kc += 32) {
        short8 a = *(const short8*)&gb[(size_t)(row0 + m) * 256 + kc + q * 8];
        #pragma unroll
        for (int nt = 0; nt < 4; ++nt) {
            short8 b = *(const short8*)&Wa1t[(size_t)(nt * 16 + m) * 256 + kc + q * 8];
            acc[nt] = __builtin_amdgcn_mfma_f32_16x16x32_bf16(a, b, acc[nt], 0, 0, 0);
        }
    }
    float part[4] = {0, 0, 0, 0};
    #pragma unroll
    for (int nt = 0; nt < 4; ++nt) {
        int col = nt * 16 + m;
        float ba1v = wbuf[O_BA1 + col];
        float wa2v = wbuf[O_WA2 + col];
        #pragma unroll
        for (int r = 0; r < 4; ++r)
            part[r] += prelu(acc[nt][r] + ba1v) * wa2v;
    }
    #pragma unroll
    for (int off = 1; off < 16; off <<= 1) {
        #pragma unroll
        for (int r = 0; r < 4; ++r)
            part[r] += __shfl_xor(part[r], off, 64);
    }
    if (m == 0) {
        float ba2v = wbuf[O_BA2];
        #pragma unroll
        for (int r = 0; r < 4; ++r) {
            int row = row0 + q * 4 + r;
            int n = row >> 2, b = row & 3;
            float v = part[r] + ba2v;
            out[8 + b * NNODE + n] = 1.f / (1.f + __expf(-v));
        }
    }
}

// ---------------- diagnostics (sampled) ----------------
__global__ __launch_bounds__(256) void k_diag(float* __restrict__ out,
        const u16* __restrict__ featb, const u16* __restrict__ gb,
        const int* __restrict__ row_ptr, const int* __restrict__ ei,
        const void* __restrict__ xsrc, int hostbad) {
    __shared__ float red[256];
    bool ei64 = probe_ei64(ei);
    bool isbf = probe_x_bf16(xsrc);
    int tid = threadIdx.x;
    float mx[2] = {0.f, 0.f};
    const u16* bufs[2] = {featb, gb};
    for (int q = 0; q < 2; ++q) {
        const u16* p = bufs[q];
        float m = 0.f;
        for (int i = tid; i < 2048; i += 256) {
            float v = u2f(p[i]);
            if (v != v) m = 1e30f;
            m = fmaxf(m, fabsf(v));
        }
        red[tid] = m;
        __syncthreads();
        for (int s2 = 128; s2 > 0; s2 >>= 1) {
            if (tid < s2) red[tid] = fmaxf(red[tid], red[tid + s2]);
            __syncthreads();
        }
        mx[q] = red[0];
        __syncthreads();
    }
    if (tid == 0) {
        int fb = (mx[0] > 1e8f || mx[0] < 1e-6f) ? 1 : 0;
        int gbad = (mx[1] > 1e8f || mx[1] < 1e-6f) ? 1 : 0;
        int cb = (row_ptr[NNODE] != NEDGE + NNODE) ? 1 : 0;
        int code = 100 * fb + 400 * gbad + 800 * cb + 6400 * hostbad;
        if (code) {
            code += 1600 * (isbf ? 0 : 1);
            code += 3200 * (ei64 ? 1 : 0);
            for (int j = 0; j < 8; ++j) out[j] = (float)code;
        }
    }
}

extern "C" void kernel_launch(void* const* d_in, const int* in_sizes, int n_in,
                              void* d_out, int out_size, void* d_ws, size_t ws_size,
                              hipStream_t stream) {
    const void* x  = d_in[0];
    const int*  ei = (const int*)d_in[1];
    float* out = (float*)d_out;

    WPtrs wp;
    for (int j = 0; j < 20; ++j) wp.p[j] = d_in[j + 2];

    char* ws = (char*)d_ws;
    size_t off = 0;
    auto alloc = [&](size_t bytes) -> void* {
        void* p = ws + off;
        off += (bytes + 255) & ~(size_t)255;
        return p;
    };
    float* wbuf    = (float*)alloc((size_t)W_TOTAL * 4);
    u16*   featb   = (u16*)  alloc((size_t)BATCH * NNODE * 64 * 2);
    u16*   xlb     = (u16*)  alloc((size_t)BATCH * NNODE * 256 * 2);
    u16*   gb      = (u16*)  alloc((size_t)BATCH * NNODE * 256 * 2);
    float* a_s     = (float*)alloc((size_t)BATCH * NNODE * 4 * 4);
    float* a_d     = (float*)alloc((size_t)BATCH * NNODE * 4 * 4);
    float* pooled  = (float*)alloc(BATCH * 256 * 4);
    u16*   cw2r    = (u16*)alloc(6144 * 2);
    u16*   W0t     = (u16*)alloc(16384 * 2);
    u16*   W1t     = (u16*)alloc(65536 * 2);
    u16*   Wa1t    = (u16*)alloc(16384 * 2);
    int*   counts  = (int*)alloc(NNODE * 4);
    int*   row_ptr = (int*)alloc((NNODE + 1) * 4);
    int*   cur     = (int*)alloc(NNODE * 4);
    int*   col_src = (int*)alloc((NEDGE + NNODE) * 4);
    int*   bsum    = (int*)alloc(128 * 4);
    (void)ws_size; (void)out_size;

    int hostbad = (n_in != 22 || in_sizes[0] != BATCH * NNODE * TLEN ||
                   in_sizes[1] != 2 * NEDGE) ? 1 : 0;

    int eg = (NEDGE + NNODE + 255) / 256;

    k_cvt<<<CVT_WBLK + 40, 256, 0, stream>>>(wp, x, wbuf, counts, pooled);
    k_prep<<<eg, 256, 0, stream>>>(wbuf, cw2r, W0t, W1t, Wa1t, ei, counts);
    k_scan1<<<40, 256, 0, stream>>>(counts, cur, bsum);
    k_scan2<<<1, 64, 0, stream>>>(bsum);
    k_scan3<<<40, 256, 0, stream>>>(counts, cur, bsum, row_ptr);
    k_fill<<<eg, 256, 0, stream>>>(ei, cur, col_src);

    k_conv<<<BATCH * NNODE / 4, 256, 0, stream>>>(x, wbuf, cw2r, featb);

    // GAT layer 0 (attention scores fused into GEMM epilogue)
    k_gemm<64, 1><<<BATCH * NNODE / 64, 256, 0, stream>>>(featb, W0t,
            wbuf + O_AS0, wbuf + O_AD0, xlb, a_s, a_d);
    k_agg<<<NNODE / 2, 256, 0, stream>>>(xlb, a_s, a_d, row_ptr, col_src, wbuf + O_B0, gb);

    // GAT layer 1 (32 rows/wave halves B traffic)
    k_gemm<256, 2><<<(BATCH * NNODE + 127) / 128, 256, 0, stream>>>(gb, W1t,
            wbuf + O_AS1, wbuf + O_AD1, xlb, a_s, a_d);
    k_agg<<<NNODE / 2, 256, 0, stream>>>(xlb, a_s, a_d, row_ptr, col_src, wbuf + O_B1, gb);

    // heads
    k_pool<<<BATCH * 64, 256, 0, stream>>>(gb, pooled);
    k_logits<<<4, 128, 0, stream>>>(pooled, wbuf, out);
    k_attr<<<BATCH * NNODE / 64, 256, 0, stream>>>(gb, Wa1t, wbuf, out);

    k_diag<<<1, 256, 0, stream>>>(out, featb, gb, row_ptr, ei, x, hostbad);
}

// Round 11
// 479.349 us; speedup vs baseline: 1.0486x; 1.0260x over previous
//
#include <hip/hip_runtime.h>
#include <hip/hip_bf16.h>
#include <math.h>

typedef __hip_bfloat16 bf16;
typedef unsigned short u16;
typedef unsigned int u32;
typedef __attribute__((ext_vector_type(8))) short short8;
typedef __attribute__((ext_vector_type(4))) float f32x4;
typedef __attribute__((ext_vector_type(2))) float f32x2;

#define BATCH 4
#define NNODE 10000
#define TLEN 128
#define NEDGE 160000
#define GDIM 256
#define NHEAD 4

// fp32 staging offsets for the 20 non-x float inputs (element offsets)
#define O_CW1 0
#define O_CB1 96
#define O_CW2 128
#define O_CB2 6272
#define O_W0  6336
#define O_AS0 22720
#define O_AD0 22976
#define O_B0  23232
#define O_W1  23488
#define O_AS1 89024
#define O_AD1 89280
#define O_B1  89536
#define O_WC1 89792
#define O_BC1 122560
#define O_WC2 122688
#define O_BC2 122944
#define O_WA1 122946
#define O_BA1 139330
#define O_WA2 139394
#define O_BA2 139458
#define W_TOTAL 139459

__device__ __forceinline__ float b2f(bf16 v) { return __bfloat162float(v); }
__device__ __forceinline__ float prelu(float v) { return 0.5f * (v + fabsf(v)); }
__device__ __forceinline__ u16 f2b(float f) {
    union { float f; u32 u; } v; v.f = f;
    u32 r = v.u + 0x7FFF + ((v.u >> 16) & 1);
    return (u16)(r >> 16);
}
__device__ __forceinline__ float u2f(u16 u) {
    union { u32 u; float f; } v; v.u = ((u32)u) << 16;
    return v.f;
}
// load one weight element, runtime dtype
__device__ __forceinline__ float ldw(const void* p, int off, bool isbf) {
    return isbf ? u2f(((const u16*)p)[off]) : ((const float*)p)[off];
}

// per-wave inline dtype probes (all waves compute identical results)
__device__ __forceinline__ bool probe_x_bf16(const void* xsrc) {
    int lane = threadIdx.x & 63;
    u16 h = ((const u16*)xsrc)[2 * lane];
    int e = (h >> 7) & 0xFF;
    unsigned long long m = __ballot(e >= 117 && e <= 130);
    return __popcll(m) >= 32;
}
__device__ __forceinline__ bool probe_ei64(const int* ei) {
    int lane = threadIdx.x & 63;
    int v = ei[2 * lane + 1];
    unsigned long long m = __ballot(v == 0);
    return __popcll(m) >= 56;
}

struct WPtrs { const void* p[20]; };

// ------ merged: wbuf fp32 staging + bf16 transposes (from source) + dst histogram ------
#define PRE_WBLK 545
#define PRE_TBLK 665   // covers max(65536, 170000) indices
__global__ __launch_bounds__(256) void k_pre(WPtrs wp, const void* __restrict__ xsrc,
        const int* __restrict__ ei, float* __restrict__ wbuf,
        u16* __restrict__ cw2r, u16* __restrict__ W0t, u16* __restrict__ W1t,
        u16* __restrict__ Wa1t, int* __restrict__ counts) {
    const int C[21] = {0,96,128,6272,6336,22720,22976,23232,23488,89024,89280,89536,
                       89792,122560,122688,122944,122946,139330,139394,139458,139459};
    bool isbf = probe_x_bf16(xsrc);
    int b = blockIdx.x;
    if (b < PRE_WBLK) {
        int i = b * 256 + threadIdx.x;
        if (i >= W_TOTAL) return;
        int j = 19;
        for (int t = 0; t < 20; ++t) { if (i < C[t + 1]) { j = t; break; } }
        wbuf[i] = ldw(wp.p[j], i - C[j], isbf);
        return;
    }
    int i = (b - PRE_WBLK) * 256 + threadIdx.x;
    if (i < 6144) {   // cw2r[c2][k'=dk*32+ci]
        int c2 = i / 96, k = i - c2 * 96, s = k >> 5, ci = k & 31;
        cw2r[i] = f2b(ldw(wp.p[2], c2 * 96 + ci * 3 + s, isbf));
    }
    if (i < 16384) {  // W0t / Wa1t, coalesced reads
        int k = i >> 8, c = i & 255;
        W0t[c * 64 + k] = f2b(ldw(wp.p[4], k * 256 + c, isbf));
        int ka = i >> 6, ca = i & 63;
        Wa1t[ca * 256 + ka] = f2b(ldw(wp.p[16], ka * 64 + ca, isbf));
    }
    if (i < 65536) {  // W1t
        int k = i >> 8, c = i & 255;
        W1t[c * 256 + k] = f2b(ldw(wp.p[8], k * 256 + c, isbf));
    }
    if (i < NEDGE + NNODE) {   // dst histogram (counts pre-zeroed by memset)
        bool ei64 = probe_ei64(ei);
        int dst;
        if (i < NEDGE) dst = ei64 ? ei[2 * (NEDGE + i)] : ei[NEDGE + i];
        else dst = i - NEDGE;
        if (dst >= 0 && dst < NNODE) atomicAdd(&counts[dst], 1);
    }
}

// ---------------- parallel scan (2 kernels; scan2 absorbed into scan3) ----------------
__global__ __launch_bounds__(256) void k_scan1(const int* __restrict__ counts,
        int* __restrict__ cur, int* __restrict__ bsum) {
    __shared__ int buf[256];
    int tid = threadIdx.x;
    int i = blockIdx.x * 256 + tid;
    int v = (i < NNODE) ? counts[i] : 0;
    buf[tid] = v;
    __syncthreads();
    for (int off = 1; off < 256; off <<= 1) {
        int t = (tid >= off) ? buf[tid - off] : 0;
        __syncthreads();
        buf[tid] += t;
        __syncthreads();
    }
    if (i < NNODE) cur[i] = buf[tid];
    if (tid == 255) bsum[blockIdx.x] = buf[255];
}
__global__ __launch_bounds__(256) void k_scan3(const int* __restrict__ counts,
        int* __restrict__ cur, const int* __restrict__ bsum, int* __restrict__ row_ptr) {
    __shared__ int pre_s;
    int tid = threadIdx.x;
    if (tid == 0) {
        int s = 0;
        for (int j = 0; j < blockIdx.x; ++j) s += bsum[j];
        pre_s = s;
    }
    __syncthreads();
    int i = blockIdx.x * 256 + tid;
    if (i >= NNODE) return;
    int incl = cur[i] + pre_s;
    row_ptr[i + 1] = incl;
    cur[i] = incl - counts[i];
    if (i == 0) row_ptr[0] = 0;
}

// ---------------- CSR fill ----------------
__global__ void k_fill(const int* __restrict__ ei,
                       int* __restrict__ cur, int* __restrict__ col_src) {
    bool ei64 = probe_ei64(ei);
    int e = blockIdx.x * 256 + threadIdx.x;
    if (e >= NEDGE + NNODE) return;
    int src, dst;
    if (e < NEDGE) {
        if (ei64) { src = ei[2 * e]; dst = ei[2 * (NEDGE + e)]; }
        else      { src = ei[e];     dst = ei[NEDGE + e]; }
    } else {
        src = dst = e - NEDGE;
    }
    if (dst < 0 || dst >= NNODE) return;
    int pos = atomicAdd(&cur[dst], 1);
    if (pos >= 0 && pos < NEDGE + NNODE) col_src[pos] = src;
}

// ---------------- fused temporal conv: R8 structure, HSTR 40, packed bf16 cvt ---------
#define HSTR 40    // R8-measured optimum for the shared-hs layout
#define WSTR 104
__global__ __launch_bounds__(256) void k_conv(const void* __restrict__ xsrc,
        const float* __restrict__ wbuf, const u16* __restrict__ cw2r,
        u16* __restrict__ featb) {
    __shared__ __align__(16) float xs[4][132];
    __shared__ float w1s[96], b1s[32], b2s[64];
    __shared__ __align__(16) u16 w2s[64 * WSTR];
    __shared__ __align__(16) u16 hs[66 * HSTR];
    __shared__ float red2[4][64];

    bool isbf = probe_x_bf16(xsrc);
    int tid = threadIdx.x;
    int wave = tid >> 6, lane = tid & 63;
    int node0 = blockIdx.x * 4;

    {
        int j = tid >> 6, p = (tid & 63) * 2;
        if (isbf) {
            u32 w = ((const u32*)xsrc)[(size_t)node0 * 64 + tid];
            xs[j][1 + p] = u2f((u16)(w & 0xFFFF));
            xs[j][2 + p] = u2f((u16)(w >> 16));
        } else {
            float2 w = ((const float2*)xsrc)[(size_t)node0 * 64 + tid];
            xs[j][1 + p] = w.x;
            xs[j][2 + p] = w.y;
        }
    }
    if (tid < 8) xs[tid >> 1][(tid & 1) ? 129 : 0] = 0.f;
    if (tid < 96) w1s[tid] = wbuf[O_CW1 + tid];
    if (tid < 32) b1s[tid] = wbuf[O_CB1 + tid];
    if (tid < 64) b2s[tid] = wbuf[O_CB2 + tid];
    for (int i = tid; i < 768; i += 256) {
        int c2 = i / 12, r = i - c2 * 12;
        *(short8*)&w2s[c2 * WSTR + r * 8] = *(const short8*)&cw2r[i * 8];
    }
    if (tid < 32) hs[tid] = 0;
    else if (tid < 64) hs[65 * HSTR + (tid - 32)] = 0;
    __syncthreads();

    int d = tid & 15, uu = tid >> 4;
    float wa0 = w1s[6 * d + 0], wa1 = w1s[6 * d + 1], wa2 = w1s[6 * d + 2];
    float wb0 = w1s[6 * d + 3], wb1 = w1s[6 * d + 4], wb2 = w1s[6 * d + 5];
    float ba = b1s[2 * d], bb = b1s[2 * d + 1];
    int m = lane & 15, q = lane >> 4;
    int trow = wave * 16 + m;

    for (int j = 0; j < 4; ++j) {
        const float* xr = &xs[j][0];
        #pragma unroll
        for (int it = 0; it < 4; ++it) {
            int u = uu + 16 * it;
            int t0 = 2 * u;
            float x0 = xr[t0], x1 = xr[t0 + 1], x2 = xr[t0 + 2], x3 = xr[t0 + 3];
            f32x2 A = {x0, x1}, Bv = {x1, x2}, Cv = {x2, x3};
            f32x2 va = {ba, ba}; va += wa0 * A; va += wa1 * Bv; va += wa2 * Cv;
            f32x2 vb = {bb, bb}; vb += wb0 * A; vb += wb1 * Bv; vb += wb2 * Cv;
            float ha = fmaxf(fmaxf(va.x, va.y), 0.f);
            float hb = fmaxf(fmaxf(vb.x, vb.y), 0.f);
            __hip_bfloat162 hp2 = __float22bfloat162_rn(make_float2(ha, hb));
            u32 pack; __builtin_memcpy(&pack, &hp2, 4);   // v_cvt_pk_bf16_f32
            *(u32*)&hs[(u + 1) * HSTR + 2 * d] = pack;
        }
        __syncthreads();

        short8 afr[3];
        #pragma unroll
        for (int s = 0; s < 3; ++s)
            afr[s] = *(const short8*)&hs[(trow + s) * HSTR + q * 8];
        float psum[4];
        #pragma unroll
        for (int nt = 0; nt < 4; ++nt) {
            int n = nt * 16 + m;
            f32x4 acc = {0.f, 0.f, 0.f, 0.f};
            #pragma unroll
            for (int s = 0; s < 3; ++s) {
                short8 bfr = *(const short8*)&w2s[n * WSTR + s * 32 + q * 8];
                acc = __builtin_amdgcn_mfma_f32_16x16x32_bf16(afr[s], bfr, acc, 0, 0, 0);
            }
            float b2v = b2s[n];
            float scl = prelu(acc[0] + b2v) + prelu(acc[1] + b2v)
                      + prelu(acc[2] + b2v) + prelu(acc[3] + b2v);
            scl += __shfl_xor(scl, 16, 64);
            scl += __shfl_xor(scl, 32, 64);
            psum[nt] = scl;
        }
        if (lane < 16) {
            #pragma unroll
            for (int nt = 0; nt < 4; ++nt)
                red2[wave][nt * 16 + lane] = psum[nt];
        }
        __syncthreads();
        if (tid < 64) {
            float tot = (red2[0][tid] + red2[1][tid] + red2[2][tid] + red2[3][tid]) * (1.f / 64.f);
            int node = node0 + j;
            int bb2 = node / NNODE, nn = node - bb2 * NNODE;
            featb[((size_t)nn * 4 + bb2) * 64 + tid] = f2b(tot);
        }
    }
}

// ------ zero-LDS MFMA GEMM, MT m-tiles per wave, fused attention scores ------
template<int K, int MT>
__global__ __launch_bounds__(256) void k_gemm(const u16* __restrict__ A,
        const u16* __restrict__ Wt, const float* __restrict__ att_s_w,
        const float* __restrict__ att_d_w, u16* __restrict__ outb,
        float* __restrict__ a_s, float* __restrict__ a_d) {
    int wave = threadIdx.x >> 6, lane = threadIdx.x & 63;
    int row0 = (blockIdx.x * 4 + wave) * 16 * MT;
    if (row0 >= BATCH * NNODE) return;
    int m = lane & 15, q = lane >> 4;
    f32x4 acc[MT][16];
    #pragma unroll
    for (int mt = 0; mt < MT; ++mt)
        #pragma unroll
        for (int nt = 0; nt < 16; ++nt) acc[mt][nt] = {0.f, 0.f, 0.f, 0.f};
    for (int kc = 0; kc < K; kc += 32) {
        short8 a[MT];
        #pragma unroll
        for (int mt = 0; mt < MT; ++mt)
            a[mt] = *(const short8*)&A[(size_t)(row0 + mt * 16 + m) * K + kc + q * 8];
        #pragma unroll
        for (int nt = 0; nt < 16; ++nt) {
            short8 b = *(const short8*)&Wt[(size_t)(nt * 16 + m) * K + kc + q * 8];
            #pragma unroll
            for (int mt = 0; mt < MT; ++mt)
                acc[mt][nt] = __builtin_amdgcn_mfma_f32_16x16x32_bf16(a[mt], b, acc[mt][nt], 0, 0, 0);
        }
    }
    #pragma unroll
    for (int mt = 0; mt < MT; ++mt) {
        int r0 = row0 + mt * 16;
        #pragma unroll
        for (int nt = 0; nt < 16; ++nt) {
            #pragma unroll
            for (int r = 0; r < 4; ++r)
                outb[(size_t)(r0 + q * 4 + r) * 256 + nt * 16 + m] = f2b(acc[mt][nt][r]);
        }
        float sh_s[4][4] = {{0}}, sh_d[4][4] = {{0}};
        #pragma unroll
        for (int nt = 0; nt < 16; ++nt) {
            int h = nt >> 2;
            int cc = (nt & 3) * 16 + m;
            float asw = att_s_w[h * 64 + cc];
            float adw = att_d_w[h * 64 + cc];
            #pragma unroll
            for (int r = 0; r < 4; ++r) {
                sh_s[h][r] += acc[mt][nt][r] * asw;
                sh_d[h][r] += acc[mt][nt][r] * adw;
            }
        }
        #pragma unroll
        for (int off = 1; off < 16; off <<= 1) {
            #pragma unroll
            for (int h = 0; h < 4; ++h)
                #pragma unroll
                for (int r = 0; r < 4; ++r) {
                    sh_s[h][r] += __shfl_xor(sh_s[h][r], off, 64);
                    sh_d[h][r] += __shfl_xor(sh_d[h][r], off, 64);
                }
        }
        if (m == 0) {
            #pragma unroll
            for (int r = 0; r < 4; ++r) {
                int row = r0 + q * 4 + r;
                float4 vs = {sh_s[0][r], sh_s[1][r], sh_s[2][r], sh_s[3][r]};
                float4 vd = {sh_d[0][r], sh_d[1][r], sh_d[2][r], sh_d[3][r]};
                *(float4*)&a_s[(size_t)row * 4] = vs;
                *(float4*)&a_d[(size_t)row * 4] = vd;
            }
        }
    }
}

// ---------------- GAT aggregation (unchanged from R10) ----------------
__global__ __launch_bounds__(256) void k_agg(const u16* __restrict__ xlb,
        const float* __restrict__ a_s, const float* __restrict__ a_d,
        const int* __restrict__ row_ptr, const int* __restrict__ col_src,
        const float* __restrict__ bias, u16* __restrict__ gb_out) {
    int wave = threadIdx.x >> 6, lane = threadIdx.x & 63;
    int dst = blockIdx.x * 2 + (wave >> 1);
    int bp = (wave & 1) * 2;
    int beg = row_ptr[dst], end = row_ptr[dst + 1];

    int c = lane & 7, g = lane >> 3;
    int bc = bp + (c >> 2), hc = c & 3;
    float adv1 = a_d[(size_t)dst * 16 + bc * 4 + hc];
    float mloc = -INFINITY;
    for (int i = beg + g; i < end; i += 8) {
        int src = min(max(col_src[i], 0), NNODE - 1);
        float e = a_s[(size_t)src * 16 + bc * 4 + hc] + adv1;
        e = (e >= 0.f) ? e : 0.2f * e;
        mloc = fmaxf(mloc, e);
    }
    mloc = fmaxf(mloc, __shfl_xor(mloc, 8, 64));
    mloc = fmaxf(mloc, __shfl_xor(mloc, 16, 64));
    mloc = fmaxf(mloc, __shfl_xor(mloc, 32, 64));

    int bl = lane >> 5;
    int s = lane & 31;
    int h = s >> 3;
    int b = bp + bl;
    float mv = __shfl(mloc, bl * 4 + h, 64);

    float advh = a_d[(size_t)dst * 16 + b * 4 + h];
    float acc[8];
    #pragma unroll
    for (int k = 0; k < 8; ++k) acc[k] = 0.f;
    float l = 0.f;

    int i = beg;
    float as_c = 0.f; short8 x_c = {0};
    if (i < end) {
        int src = min(max(col_src[i], 0), NNODE - 1);
        as_c = a_s[(size_t)src * 16 + b * 4 + h];
        x_c = *(const short8*)&xlb[((size_t)src * 4 + b) * 256 + s * 8];
    }
    while (i < end) {
        int inext = i + 1;
        float as_n = 0.f; short8 x_n = {0};
        if (inext < end) {
            int src = min(max(col_src[inext], 0), NNODE - 1);
            as_n = a_s[(size_t)src * 16 + b * 4 + h];
            x_n = *(const short8*)&xlb[((size_t)src * 4 + b) * 256 + s * 8];
        }
        float e = as_c + advh;
        e = (e >= 0.f) ? e : 0.2f * e;
        float p = __expf(e - mv);
        l += p;
        #pragma unroll
        for (int k = 0; k < 8; ++k) acc[k] += p * u2f((u16)x_c[k]);
        as_c = as_n; x_c = x_n;
        i = inext;
    }
    float rl = 1.f / (l + 1e-16f);
    short8 o;
    #pragma unroll
    for (int k = 0; k < 8; ++k)
        o[k] = (short)f2b(prelu(acc[k] * rl + bias[s * 8 + k]));
    *(short8*)&gb_out[((size_t)dst * 4 + b) * 256 + s * 8] = o;
}

// ---------------- attribution head (blocks <625) + pooled sum (blocks >=625) ----------
__global__ __launch_bounds__(256) void k_attrpool(const u16* __restrict__ gb,
        const u16* __restrict__ Wa1t, const float* __restrict__ wbuf,
        float* __restrict__ out, float* __restrict__ pooled) {
    if (blockIdx.x >= 625) {   // pool part
        int pb = blockIdx.x - 625;
        int b = pb >> 6;
        int chunk = pb & 63;
        int cch = threadIdx.x;
        int n0 = chunk * 157;
        int n1 = min(NNODE, n0 + 157);
        float acc = 0.f;
        for (int n = n0; n < n1; ++n)
            acc += u2f(gb[((size_t)n * 4 + b) * 256 + cch]);
        atomicAdd(&pooled[b * 256 + cch], acc);
        return;
    }
    int wave = threadIdx.x >> 6, lane = threadIdx.x & 63;
    int row0 = (blockIdx.x * 4 + wave) * 16;
    int m = lane & 15, q = lane >> 4;
    f32x4 acc[4];
    #pragma unroll
    for (int nt = 0; nt < 4; ++nt) acc[nt] = {0.f, 0.f, 0.f, 0.f};
    for (int kc = 0; kc < 256; kc += 32) {
        short8 a = *(const short8*)&gb[(size_t)(row0 + m) * 256 + kc + q * 8];
        #pragma unroll
        for (int nt = 0; nt < 4; ++nt) {
            short8 b = *(const short8*)&Wa1t[(size_t)(nt * 16 + m) * 256 + kc + q * 8];
            acc[nt] = __builtin_amdgcn_mfma_f32_16x16x32_bf16(a, b, acc[nt], 0, 0, 0);
        }
    }
    float part[4] = {0, 0, 0, 0};
    #pragma unroll
    for (int nt = 0; nt < 4; ++nt) {
        int col = nt * 16 + m;
        float ba1v = wbuf[O_BA1 + col];
        float wa2v = wbuf[O_WA2 + col];
        #pragma unroll
        for (int r = 0; r < 4; ++r)
            part[r] += prelu(acc[nt][r] + ba1v) * wa2v;
    }
    #pragma unroll
    for (int off = 1; off < 16; off <<= 1) {
        #pragma unroll
        for (int r = 0; r < 4; ++r)
            part[r] += __shfl_xor(part[r], off, 64);
    }
    if (m == 0) {
        float ba2v = wbuf[O_BA2];
        #pragma unroll
        for (int r = 0; r < 4; ++r) {
            int row = row0 + q * 4 + r;
            int n = row >> 2, b = row & 3;
            float v = part[r] + ba2v;
            out[8 + b * NNODE + n] = 1.f / (1.f + __expf(-v));
        }
    }
}

// ---------------- classification head (blocks 0-3) + diagnostics (block 4) ----------
__global__ __launch_bounds__(128) void k_logits(const float* __restrict__ pooled,
        const float* __restrict__ wbuf, float* __restrict__ out,
        const u16* __restrict__ featb, const u16* __restrict__ gb,
        const int* __restrict__ row_ptr, const int* __restrict__ ei,
        const void* __restrict__ xsrc, int hostbad) {
    int tid = threadIdx.x;
    if (blockIdx.x == 4) {   // sampled diagnostics
        __shared__ float red[128];
        bool ei64 = probe_ei64(ei);
        bool isbf = probe_x_bf16(xsrc);
        float mx[2] = {0.f, 0.f};
        const u16* bufs[2] = {featb, gb};
        for (int qq = 0; qq < 2; ++qq) {
            const u16* p = bufs[qq];
            float m = 0.f;
            for (int i = tid; i < 2048; i += 128) {
                float v = u2f(p[i]);
                if (v != v) m = 1e30f;
                m = fmaxf(m, fabsf(v));
            }
            red[tid] = m;
            __syncthreads();
            for (int s2 = 64; s2 > 0; s2 >>= 1) {
                if (tid < s2) red[tid] = fmaxf(red[tid], red[tid + s2]);
                __syncthreads();
            }
            mx[qq] = red[0];
            __syncthreads();
        }
        if (tid == 0) {
            int fb = (mx[0] > 1e8f || mx[0] < 1e-6f) ? 1 : 0;
            int gbad = (mx[1] > 1e8f || mx[1] < 1e-6f) ? 1 : 0;
            int cb = (row_ptr[NNODE] != NEDGE + NNODE) ? 1 : 0;
            int code = 100 * fb + 400 * gbad + 800 * cb + 6400 * hostbad;
            if (code) {
                code += 1600 * (isbf ? 0 : 1);
                code += 3200 * (ei64 ? 1 : 0);
                for (int j = 0; j < 8; ++j) out[j] = (float)code;
            }
        }
        return;
    }
    __shared__ float pm[256];
    __shared__ float red4[4];
    int b = blockIdx.x;
    pm[tid] = pooled[b * 256 + tid] * (1.f / NNODE);
    pm[tid + 128] = pooled[b * 256 + tid + 128] * (1.f / NNODE);
    __syncthreads();
    float acc = wbuf[O_BC1 + tid];
    #pragma unroll 4
    for (int k = 0; k < 256; ++k)
        acc += pm[k] * wbuf[O_WC1 + k * 128 + tid];
    float hv = prelu(acc);
    float p0 = hv * wbuf[O_WC2 + tid * 2];
    float p1 = hv * wbuf[O_WC2 + tid * 2 + 1];
    #pragma unroll
    for (int off = 32; off > 0; off >>= 1) {
        p0 += __shfl_xor(p0, off, 64);
        p1 += __shfl_xor(p1, off, 64);
    }
    int wv = tid >> 6, lane = tid & 63;
    if (lane == 0) { red4[wv * 2] = p0; red4[wv * 2 + 1] = p1; }
    __syncthreads();
    if (tid < 2)
        out[b * 2 + tid] = red4[tid] + red4[2 + tid] + wbuf[O_BC2 + tid];
}

extern "C" void kernel_launch(void* const* d_in, const int* in_sizes, int n_in,
                              void* d_out, int out_size, void* d_ws, size_t ws_size,
                              hipStream_t stream) {
    const void* x  = d_in[0];
    const int*  ei = (const int*)d_in[1];
    float* out = (float*)d_out;

    WPtrs wp;
    for (int j = 0; j < 20; ++j) wp.p[j] = d_in[j + 2];

    char* ws = (char*)d_ws;
    size_t off = 0;
    auto alloc = [&](size_t bytes) -> void* {
        void* p = ws + off;
        off += (bytes + 255) & ~(size_t)255;
        return p;
    };
    float* wbuf    = (float*)alloc((size_t)W_TOTAL * 4);
    u16*   featb   = (u16*)  alloc((size_t)BATCH * NNODE * 64 * 2);
    u16*   xlb     = (u16*)  alloc((size_t)BATCH * NNODE * 256 * 2);
    u16*   gb      = (u16*)  alloc((size_t)BATCH * NNODE * 256 * 2);
    float* a_s     = (float*)alloc((size_t)BATCH * NNODE * 4 * 4);
    float* a_d     = (float*)alloc((size_t)BATCH * NNODE * 4 * 4);
    u16*   cw2r    = (u16*)alloc(6144 * 2);
    u16*   W0t     = (u16*)alloc(16384 * 2);
    u16*   W1t     = (u16*)alloc(65536 * 2);
    u16*   Wa1t    = (u16*)alloc(16384 * 2);
    // counts and pooled ADJACENT: one memset zeroes both
    int*   counts  = (int*)alloc(NNODE * 4);           // 40000 -> 40192 padded
    float* pooled  = (float*)alloc(BATCH * 256 * 4);   // 4096
    int*   row_ptr = (int*)alloc((NNODE + 1) * 4);
    int*   cur     = (int*)alloc(NNODE * 4);
    int*   col_src = (int*)alloc((NEDGE + NNODE) * 4);
    int*   bsum    = (int*)alloc(64 * 4);
    (void)ws_size; (void)out_size;

    int hostbad = (n_in != 22 || in_sizes[0] != BATCH * NNODE * TLEN ||
                   in_sizes[1] != 2 * NEDGE) ? 1 : 0;

    int eg = (NEDGE + NNODE + 255) / 256;

    // zero counts(+pad)+pooled in one capture-safe memset node
    hipMemsetAsync(counts, 0, 40192 + 4096, stream);

    k_pre<<<PRE_WBLK + PRE_TBLK, 256, 0, stream>>>(wp, x, ei, wbuf, cw2r, W0t, W1t, Wa1t, counts);
    k_scan1<<<40, 256, 0, stream>>>(counts, cur, bsum);
    k_scan3<<<40, 256, 0, stream>>>(counts, cur, bsum, row_ptr);
    k_fill<<<eg, 256, 0, stream>>>(ei, cur, col_src);

    k_conv<<<BATCH * NNODE / 4, 256, 0, stream>>>(x, wbuf, cw2r, featb);

    // GAT layer 0 (attention scores fused into GEMM epilogue)
    k_gemm<64, 1><<<BATCH * NNODE / 64, 256, 0, stream>>>(featb, W0t,
            wbuf + O_AS0, wbuf + O_AD0, xlb, a_s, a_d);
    k_agg<<<NNODE / 2, 256, 0, stream>>>(xlb, a_s, a_d, row_ptr, col_src, wbuf + O_B0, gb);

    // GAT layer 1 (32 rows/wave halves B traffic)
    k_gemm<256, 2><<<(BATCH * NNODE + 127) / 128, 256, 0, stream>>>(gb, W1t,
            wbuf + O_AS1, wbuf + O_AD1, xlb, a_s, a_d);
    k_agg<<<NNODE / 2, 256, 0, stream>>>(xlb, a_s, a_d, row_ptr, col_src, wbuf + O_B1, gb);

    // heads: attr + pool merged; logits + diag merged
    k_attrpool<<<625 + 256, 256, 0, stream>>>(gb, Wa1t, wbuf, out, pooled);
    k_logits<<<5, 128, 0, stream>>>(pooled, wbuf, out, featb, gb, row_ptr, ei, x, hostbad);
}